// Round 3
// baseline (340.602 us; speedup 1.0000x reference)
//
#include <hip/hip_runtime.h>

#define RED_THREADS 512

// One pipeline stage: the 7 per-lane neighbor scalars + wave-uniform point.
struct PtData {
    float vx, vy, vz, nx, ny, nz, s, px, py, pz;
};

// Consume one fully-loaded stage: quartic-kernel weight, weighted dot,
// 64-lane butterfly reduce, accumulate sdf^2 into the right batch slot.
__device__ __forceinline__ void consume_pt(
    const PtData& A, bool lk, int pt, int P, float& acc0, float& acc1)
{
    const float dx = A.px - A.vx;
    const float dy = A.py - A.vy;
    const float dz = A.pz - A.vz;
    const float d2 = dx * dx + dy * dy + dz * dz;
    const float wq = 1.0f - d2 / A.s;
    const float w2 = wq * wq;
    const float phi = (d2 < A.s) ? (w2 * w2) : 1e-18f;
    const float dot = A.nx * dx + A.ny * dy + A.nz * dz;
    float num = lk ? (phi * dot) : 0.f;
    float den = lk ? phi : 0.f;
    #pragma unroll
    for (int off = 32; off >= 1; off >>= 1) {
        num += __shfl_xor(num, off, 64);
        den += __shfl_xor(den, off, 64);
    }
    const float sdf = num / den;
    const float s2  = sdf * sdf;
    if (pt < P) acc0 += s2; else acc1 += s2;   // pt is wave-uniform
}

// Persistent-wave SDF kernel, depth-3 software pipeline, branch-free hot loop.
// Lanes 60..63 are clamped to neighbor 59 (loads always valid, results masked
// at compute), so the in-loop prefetch loads are UNCONDITIONAL — nothing stops
// the compiler from keeping all 3 stages resident in VGPRs. A
// sched_barrier(0) after the prefetch cluster pins the loads above the
// compute so they cannot be re-sunk to their use point (the R1/R2 failure:
// VGPR_Count 24/32 proved the guarded pipeline was collapsed to load-at-use).
// Per point the compiler merges vp[0..2]/qp[0..2]/pp[0..2] into dwordx3 →
// 4 VMEM instructions, 8 outstanding at the consume point → counted vmcnt.
__global__ __launch_bounds__(256) void sdf_main(
    const float* __restrict__ points,
    const float* __restrict__ v,
    const float* __restrict__ vn,
    const float* __restrict__ sr,
    float* __restrict__ ws,
    int NP, int P, int totalWaves, int slots, int slotStride)
{
    constexpr int K = 60;
    const int lane  = threadIdx.x & 63;
    const int wid   = blockIdx.x * 4 + (threadIdx.x >> 6);
    const bool lk   = lane < K;
    const int laneK = lk ? lane : (K - 1);   // clamp: lanes >=K load dup data

    const int stride   = totalWaves;
    const size_t vstep = (size_t)stride * (K * 3);
    const size_t sstep = (size_t)stride * K;
    const size_t pstep = (size_t)stride * 3;

    int pt = wid;
    if (pt >= NP) return;

    const float* vp = v      + (size_t)pt * (K * 3) + 3 * laneK;
    const float* qp = vn     + (size_t)pt * (K * 3) + 3 * laneK;
    const float* sp = sr     + (size_t)pt * K       + laneK;
    const float* pp = points + (size_t)pt * 3;

    // ---- prologue: stage A (guaranteed valid), stage B (guarded) ----
    PtData A, B;
    A.vx = vp[0]; A.vy = vp[1]; A.vz = vp[2];
    A.nx = qp[0]; A.ny = qp[1]; A.nz = qp[2];
    A.s  = sp[0];
    A.px = pp[0]; A.py = pp[1]; A.pz = pp[2];

    B.vx = B.vy = B.vz = 0.f;
    B.nx = B.ny = B.nz = 0.f;
    B.s  = 1.f;
    B.px = B.py = B.pz = 0.f;
    if (pt + stride < NP) {
        B.vx = vp[vstep + 0]; B.vy = vp[vstep + 1]; B.vz = vp[vstep + 2];
        B.nx = qp[vstep + 0]; B.ny = qp[vstep + 1]; B.nz = qp[vstep + 2];
        B.s  = sp[sstep];
        B.px = pp[pstep + 0]; B.py = pp[pstep + 1]; B.pz = pp[pstep + 2];
    }

    // stage-C pointers (the only addresses maintained in the hot loop)
    const float* vpc = vp + 2 * vstep;
    const float* qpc = qp + 2 * vstep;
    const float* spc = sp + 2 * sstep;
    const float* ppc = pp + 2 * pstep;

    float acc0 = 0.f, acc1 = 0.f;

    // ---- hot loop: unconditional prefetch of stage C, compute stage A ----
    while (pt + 2 * stride < NP) {
        PtData C;
        C.vx = vpc[0]; C.vy = vpc[1]; C.vz = vpc[2];
        C.nx = qpc[0]; C.ny = qpc[1]; C.nz = qpc[2];
        C.s  = spc[0];
        C.px = ppc[0]; C.py = ppc[1]; C.pz = ppc[2];
        __builtin_amdgcn_sched_barrier(0);   // pin loads above the compute

        consume_pt(A, lk, pt, P, acc0, acc1);

        A = B; B = C;
        vpc += vstep; qpc += vstep; spc += sstep; ppc += pstep;
        pt += stride;
    }

    // ---- epilogue: drain stages A and (maybe) B ----
    consume_pt(A, lk, pt, P, acc0, acc1);
    if (pt + stride < NP)
        consume_pt(B, lk, pt + stride, P, acc0, acc1);

    if (lane == 0) {
        const int slot = wid & (slots - 1);
        atomicAdd(&ws[slot * slotStride + 0], acc0);
        atomicAdd(&ws[slot * slotStride + 1], acc1);
    }
}

// Single-block final reduction over `slots` partial sums per batch index.
__global__ __launch_bounds__(RED_THREADS) void sdf_reduce(
    const float* __restrict__ ws, float* __restrict__ out,
    int N, int slots, int slotStride)
{
    __shared__ float sm0[RED_THREADS];
    __shared__ float sm1[RED_THREADS];
    const int tid = threadIdx.x;
    float a = 0.f, b = 0.f;
    for (int s = tid; s < slots; s += RED_THREADS) {
        a += ws[s * slotStride + 0];
        if (N > 1) b += ws[s * slotStride + 1];
    }
    sm0[tid] = a;
    sm1[tid] = b;
    __syncthreads();
    #pragma unroll
    for (int s = RED_THREADS / 2; s >= 1; s >>= 1) {
        if (tid < s) {
            sm0[tid] += sm0[tid + s];
            sm1[tid] += sm1[tid + s];
        }
        __syncthreads();
    }
    if (tid == 0) {
        out[0] = sm0[0];
        if (N > 1) out[1] = sm1[0];
    }
}

extern "C" void kernel_launch(void* const* d_in, const int* in_sizes, int n_in,
                              void* d_out, int out_size, void* d_ws, size_t ws_size,
                              hipStream_t stream) {
    const float* points = (const float*)d_in[0];
    const float* v      = (const float*)d_in[1];
    const float* vn     = (const float*)d_in[2];
    const float* sr     = (const float*)d_in[3];
    float* out = (float*)d_out;
    float* ws  = (float*)d_ws;

    const int NP = in_sizes[0] / 3;        // N*P total points (200000)
    const int N  = out_size;               // 2
    const int P  = NP / N;                 // 100000

    // Atomic-scatter geometry: one 64-B line per slot when workspace allows.
    int slots = 512, slotStride = 16;      // 32 KiB
    if (ws_size < (size_t)(slots * slotStride * sizeof(float))) {
        slots = 256; slotStride = 2;       // 2 KiB fallback
    }

    hipMemsetAsync(ws, 0, (size_t)slots * slotStride * sizeof(float), stream);

    // Persistent grid: 2048 blocks x 4 waves = 8192 waves (32 waves/CU),
    // each wave grid-strides over ~NP/8192 points.
    int blocks = (NP + 3) / 4;
    if (blocks > 2048) blocks = 2048;
    const int totalWaves = blocks * 4;

    sdf_main<<<blocks, 256, 0, stream>>>(points, v, vn, sr, ws, NP, P,
                                         totalWaves, slots, slotStride);
    sdf_reduce<<<1, RED_THREADS, 0, stream>>>(ws, out, N, slots, slotStride);
}

// Round 5
// 334.256 us; speedup vs baseline: 1.0190x; 1.0190x over previous
//
#include <hip/hip_runtime.h>

#define RED_THREADS 512

// One pipeline stage: the 7 per-lane neighbor scalars + wave-uniform point.
struct PtData {
    float vx, vy, vz, nx, ny, nz, s, px, py, pz;
};

// One DPP-accumulate step: x += dpp_move(x). Pure VALU (v_add_f32 + DPP),
// no LDS pipe. Template params so __builtin_amdgcn_update_dpp gets the
// required integer-constant arguments (R4 compile failure).
template <int Ctrl, int RowMask, int BankMask, bool BoundZero>
__device__ __forceinline__ float dpp_add(float x)
{
    int xi = __builtin_bit_cast(int, x);
    int yi = __builtin_amdgcn_update_dpp(0, xi, Ctrl, RowMask, BankMask,
                                         BoundZero);
    return x + __builtin_bit_cast(float, yi);
}

// Canonical GCN wave64 funnel reduction (GCN3 ISA doc / rocPRIM):
// 4x row_shr within rows of 16, then row_bcast:15 / row_bcast:31 to cross
// rows. Total lands in lane 63. 6 VALU ops, ~50 cy dependent chain —
// replaces the 6-op ds_swizzle butterfly (~400 cy, LDS pipe).
__device__ __forceinline__ float wave_sum_to_lane63(float x)
{
    x = dpp_add<0x111, 0xf, 0xf, true >(x);   // row_shr:1
    x = dpp_add<0x112, 0xf, 0xf, true >(x);   // row_shr:2
    x = dpp_add<0x114, 0xf, 0xf, true >(x);   // row_shr:4
    x = dpp_add<0x118, 0xf, 0xf, true >(x);   // row_shr:8
    x = dpp_add<0x142, 0xa, 0xf, false>(x);   // row_bcast:15 -> rows 1,3
    x = dpp_add<0x143, 0xc, 0xf, false>(x);   // row_bcast:31 -> rows 2,3
    return x;                                  // lane 63 = full-wave sum
}

// Consume one fully-loaded stage. Only lane 63 holds the reduced sums;
// it accumulates sdf^2 into the wave-private accumulators.
__device__ __forceinline__ void consume_pt(
    const PtData& A, bool lk, int pt, int P, float& acc0, float& acc1)
{
    const float dx = A.px - A.vx;
    const float dy = A.py - A.vy;
    const float dz = A.pz - A.vz;
    const float d2 = dx * dx + dy * dy + dz * dz;
    const float wq = 1.0f - d2 / A.s;
    const float w2 = wq * wq;
    const float phi = (d2 < A.s) ? (w2 * w2) : 1e-18f;
    const float dot = A.nx * dx + A.ny * dy + A.nz * dz;
    // lanes 60..63 carry duplicated neighbor-59 data: mask them out
    float num = lk ? (phi * dot) : 0.f;
    float den = lk ? phi : 0.f;
    num = wave_sum_to_lane63(num);
    den = wave_sum_to_lane63(den);
    const float sdf = num / den;             // meaningful in lane 63 only
    const float s2  = sdf * sdf;
    if (pt < P) acc0 += s2; else acc1 += s2; // pt is wave-uniform
}

// Persistent-wave SDF kernel, depth-3 software pipeline, branch-free hot
// loop (lanes 60..63 clamped to neighbor 59 so in-loop loads are
// unconditional). No sched_barrier — R3 showed pinning the scheduler
// regressed 112->130 us. DPP reduction removes the per-point serial
// LDS-pipe chain shared by all previous variants.
__global__ __launch_bounds__(256) void sdf_main(
    const float* __restrict__ points,
    const float* __restrict__ v,
    const float* __restrict__ vn,
    const float* __restrict__ sr,
    float* __restrict__ ws,
    int NP, int P, int totalWaves, int slots, int slotStride)
{
    constexpr int K = 60;
    const int lane  = threadIdx.x & 63;
    const int wid   = blockIdx.x * 4 + (threadIdx.x >> 6);
    const bool lk   = lane < K;
    const int laneK = lk ? lane : (K - 1);

    const int stride   = totalWaves;
    const size_t vstep = (size_t)stride * (K * 3);
    const size_t sstep = (size_t)stride * K;
    const size_t pstep = (size_t)stride * 3;

    int pt = wid;
    if (pt >= NP) return;

    const float* vp = v      + (size_t)pt * (K * 3) + 3 * laneK;
    const float* qp = vn     + (size_t)pt * (K * 3) + 3 * laneK;
    const float* sp = sr     + (size_t)pt * K       + laneK;
    const float* pp = points + (size_t)pt * 3;

    // ---- prologue: stage A (valid), stage B (guarded) ----
    PtData A, B;
    A.vx = vp[0]; A.vy = vp[1]; A.vz = vp[2];
    A.nx = qp[0]; A.ny = qp[1]; A.nz = qp[2];
    A.s  = sp[0];
    A.px = pp[0]; A.py = pp[1]; A.pz = pp[2];

    B.vx = B.vy = B.vz = 0.f;
    B.nx = B.ny = B.nz = 0.f;
    B.s  = 1.f;
    B.px = B.py = B.pz = 0.f;
    if (pt + stride < NP) {
        B.vx = vp[vstep + 0]; B.vy = vp[vstep + 1]; B.vz = vp[vstep + 2];
        B.nx = qp[vstep + 0]; B.ny = qp[vstep + 1]; B.nz = qp[vstep + 2];
        B.s  = sp[sstep];
        B.px = pp[pstep + 0]; B.py = pp[pstep + 1]; B.pz = pp[pstep + 2];
    }

    const float* vpc = vp + 2 * vstep;
    const float* qpc = qp + 2 * vstep;
    const float* spc = sp + 2 * sstep;
    const float* ppc = pp + 2 * pstep;

    float acc0 = 0.f, acc1 = 0.f;

    // ---- hot loop: unconditional stage-C prefetch, compute stage A ----
    while (pt + 2 * stride < NP) {
        PtData C;
        C.vx = vpc[0]; C.vy = vpc[1]; C.vz = vpc[2];
        C.nx = qpc[0]; C.ny = qpc[1]; C.nz = qpc[2];
        C.s  = spc[0];
        C.px = ppc[0]; C.py = ppc[1]; C.pz = ppc[2];

        consume_pt(A, lk, pt, P, acc0, acc1);

        A = B; B = C;
        vpc += vstep; qpc += vstep; spc += sstep; ppc += pstep;
        pt += stride;
    }

    // ---- epilogue: drain A and (maybe) B ----
    consume_pt(A, lk, pt, P, acc0, acc1);
    if (pt + stride < NP)
        consume_pt(B, lk, pt + stride, P, acc0, acc1);

    if (lane == 63) {   // reduction result lives in lane 63
        const int slot = wid & (slots - 1);
        atomicAdd(&ws[slot * slotStride + 0], acc0);
        atomicAdd(&ws[slot * slotStride + 1], acc1);
    }
}

// Single-block final reduction over `slots` partial sums per batch index.
__global__ __launch_bounds__(RED_THREADS) void sdf_reduce(
    const float* __restrict__ ws, float* __restrict__ out,
    int N, int slots, int slotStride)
{
    __shared__ float sm0[RED_THREADS];
    __shared__ float sm1[RED_THREADS];
    const int tid = threadIdx.x;
    float a = 0.f, b = 0.f;
    for (int s = tid; s < slots; s += RED_THREADS) {
        a += ws[s * slotStride + 0];
        if (N > 1) b += ws[s * slotStride + 1];
    }
    sm0[tid] = a;
    sm1[tid] = b;
    __syncthreads();
    #pragma unroll
    for (int s = RED_THREADS / 2; s >= 1; s >>= 1) {
        if (tid < s) {
            sm0[tid] += sm0[tid + s];
            sm1[tid] += sm1[tid + s];
        }
        __syncthreads();
    }
    if (tid == 0) {
        out[0] = sm0[0];
        if (N > 1) out[1] = sm1[0];
    }
}

extern "C" void kernel_launch(void* const* d_in, const int* in_sizes, int n_in,
                              void* d_out, int out_size, void* d_ws, size_t ws_size,
                              hipStream_t stream) {
    const float* points = (const float*)d_in[0];
    const float* v      = (const float*)d_in[1];
    const float* vn     = (const float*)d_in[2];
    const float* sr     = (const float*)d_in[3];
    float* out = (float*)d_out;
    float* ws  = (float*)d_ws;

    const int NP = in_sizes[0] / 3;        // N*P total points (200000)
    const int N  = out_size;               // 2
    const int P  = NP / N;                 // 100000

    int slots = 512, slotStride = 16;      // 32 KiB: one cache line per slot
    if (ws_size < (size_t)(slots * slotStride * sizeof(float))) {
        slots = 256; slotStride = 2;       // 2 KiB fallback
    }

    (void)hipMemsetAsync(ws, 0, (size_t)slots * slotStride * sizeof(float),
                         stream);

    // Persistent grid: 2048 blocks x 4 waves = 8192 waves (32 waves/CU).
    int blocks = (NP + 3) / 4;
    if (blocks > 2048) blocks = 2048;
    const int totalWaves = blocks * 4;

    sdf_main<<<blocks, 256, 0, stream>>>(points, v, vn, sr, ws, NP, P,
                                         totalWaves, slots, slotStride);
    sdf_reduce<<<1, RED_THREADS, 0, stream>>>(ws, out, N, slots, slotStride);
}